// Round 5
// baseline (518.304 us; speedup 1.0000x reference)
//
#include <hip/hip_runtime.h>

#define S_TOTAL 17064
#define NB 16
#define NC 80
#define QPB 4266              // location-quads per batch image (sum hw/4)
#define NXQ 17                // quad-chunks of 256: 17*256=4352 >= 4266
#define NCCH 20               // class chunks of 4 classes each
#define NCH (NCCH + 1)        // + 1 cnt/reg chunk
#define TOTAL_BLOCKS (NXQ * NCH * NB)   // 5712

typedef float vfloat4 __attribute__((ext_vector_type(4)));

struct Ptrs {
    const float* cls[5];
    const float* cnt[5];
    const float* reg[5];
    const float* cnt_t;   // [B,S,1]
    const float* reg_t;   // [B,S,4]
    const int*   cls_t;   // [B,S,1]
    float*       ws;      // [0:16) cls, [16:32) cnt, [32:48) reg, [48:64) pos, [64] counter
    float*       out;
};

__device__ __forceinline__ float focal_term(float x, bool o) {
    const float xs = o ? x : -x;            // p_t = sigmoid(xs)
    const float af = o ? 0.25f : 0.75f;
    const float em = __expf(-xs);
    const float pt = 1.0f / (1.0f + em);
    const float q  = em * pt;               // 1 - p_t
    return af * q * q * __logf(1.0f + em);  // -af*(1-pt)^2*log(pt)
}

__device__ __forceinline__ float giou_term(float pl, float pt_, float pr, float pb,
                                           float tl, float tt, float tr, float tb) {
    const float overlap = fmaxf(fminf(pr, tr) + fminf(pl, tl), 0.0f) *
                          fmaxf(fminf(pb, tb) + fminf(pt_, tt), 0.0f);
    const float area1 = (pr + pl) * (pb + pt_);
    const float area2 = (tr + tl) * (tb + tt);
    const float uni = area1 + area2 - overlap;
    const float iou = overlap / uni;
    const float ga = fmaxf(fmaxf(pr, tr) + fmaxf(pl, tl), 0.0f) *
                     fmaxf(fmaxf(pb, tb) + fmaxf(pt_, tt), 0.0f);
    const float giou = iou - (ga - uni) / fmaxf(ga, 1e-10f);
    return 1.0f - giou;
}

__device__ __forceinline__ float bce_term(float x, float t) {
    return fmaxf(x, 0.0f) - x * t + __logf(1.0f + __expf(-fabsf(x)));
}

// grid: (NXQ, NCH, NB). ch<NCCH: 4-class focal chunk. ch==NCCH: cnt+GIoU chunk.
// 4-class chunks (buf[4] = 16 VGPRs): rounds 1/4 showed a persistent
// 32-VGPR allocation with deterministic 204 KB spill traffic when the focal
// path carried buf[8] (32 VGPRs of buffer alone). This working set fits a
// 32-VGPR budget with zero scratch, so the kernel is correct-by-construction
// against whatever drove that allocation. Grid 5712 blocks keeps TLP high.
__global__ __launch_bounds__(256) void fcos_main(Ptrs p) {
    const int xq = blockIdx.x;              // 0..16 quad-chunk
    const int ch = blockIdx.y;              // 0..20
    const int b  = blockIdx.z;              // 0..15
    const int fq = xq * 256 + (int)threadIdx.x;  // flat quad id within image

    // flat quad -> (level, s0)
    int lvl, qb, hw, off;
    if (fq < 3200)      { lvl = 0; qb = 0;    hw = 12800; off = 0;     }
    else if (fq < 4000) { lvl = 1; qb = 3200; hw = 3200;  off = 12800; }
    else if (fq < 4200) { lvl = 2; qb = 4000; hw = 800;   off = 16000; }
    else if (fq < 4252) { lvl = 3; qb = 4200; hw = 208;   off = 16800; }
    else                { lvl = 4; qb = 4252; hw = 56;    off = 17008; }
    const bool active = (fq < QPB);

    float r0 = 0.f, r1 = 0.f, r2 = 0.f;     // cls | (cnt, reg, pos)

    if (active) {
        const int s0  = (fq - qb) << 2;
        const int gs0 = b * S_TOTAL + off + s0;

        if (ch < NCCH) {
            // ---- 4-class focal chunk: 4 loads in flight, ~28 live VGPRs ----
            const int c0 = ch * 4;
            const int4 tq = *(const int4*)(p.cls_t + gs0);
            const float* cp = p.cls[lvl] + (size_t)((b * NC + c0) * hw + s0);

            vfloat4 buf[4];
            #pragma unroll
            for (int j = 0; j < 4; ++j)
                buf[j] = *(const vfloat4*)(cp + (size_t)(j * hw));

            float a0 = 0.f, a1 = 0.f, a2 = 0.f, a3 = 0.f;
            #pragma unroll
            for (int j = 0; j < 4; ++j) {
                const int c1 = c0 + j + 1;
                a0 += focal_term(buf[j].x, tq.x == c1);
                a1 += focal_term(buf[j].y, tq.y == c1);
                a2 += focal_term(buf[j].z, tq.z == c1);
                a3 += focal_term(buf[j].w, tq.w == c1);
            }
            r0 = (a0 + a1) + (a2 + a3);
        } else {
            // ---- cnt BCE + GIoU chunk ----
            const float4 tC  = *(const float4*)(p.cnt_t + gs0);
            const float4 xc  = *(const float4*)(p.cnt[lvl] + (size_t)(b * hw + s0));
            const float m0 = (tC.x > -1.0f) ? 1.0f : 0.0f;
            const float m1 = (tC.y > -1.0f) ? 1.0f : 0.0f;
            const float m2 = (tC.z > -1.0f) ? 1.0f : 0.0f;
            const float m3 = (tC.w > -1.0f) ? 1.0f : 0.0f;
            r2 = m0 + m1 + m2 + m3;
            r0 = bce_term(xc.x, tC.x) * m0 + bce_term(xc.y, tC.y) * m1 +
                 bce_term(xc.z, tC.z) * m2 + bce_term(xc.w, tC.w) * m3;

            const float* rp  = p.reg[lvl] + (size_t)(b * 4 * hw + s0);
            const float4 pl  = *(const float4*)(rp);
            const float4 pt_ = *(const float4*)(rp + (size_t)hw);
            const float4 pr  = *(const float4*)(rp + (size_t)(2 * hw));
            const float4 pb  = *(const float4*)(rp + (size_t)(3 * hw));
            const float4 t0  = *(const float4*)(p.reg_t + (size_t)(gs0 + 0) * 4);
            const float4 t1  = *(const float4*)(p.reg_t + (size_t)(gs0 + 1) * 4);
            const float4 t2  = *(const float4*)(p.reg_t + (size_t)(gs0 + 2) * 4);
            const float4 t3  = *(const float4*)(p.reg_t + (size_t)(gs0 + 3) * 4);

            r1 = giou_term(pl.x, pt_.x, pr.x, pb.x, t0.x, t0.y, t0.z, t0.w) * m0 +
                 giou_term(pl.y, pt_.y, pr.y, pb.y, t1.x, t1.y, t1.z, t1.w) * m1 +
                 giou_term(pl.z, pt_.z, pr.z, pb.z, t2.x, t2.y, t2.z, t2.w) * m2 +
                 giou_term(pl.w, pt_.w, pr.w, pb.w, t3.x, t3.y, t3.z, t3.w) * m3;
        }
    }

    // ---- block reduction (3 values) ----
    #pragma unroll
    for (int d = 32; d; d >>= 1) {
        r0 += __shfl_down(r0, d);
        r1 += __shfl_down(r1, d);
        r2 += __shfl_down(r2, d);
    }

    __shared__ float red[3][4];
    const int wave = threadIdx.x >> 6;
    const int lane = threadIdx.x & 63;
    if (lane == 0) {
        red[0][wave] = r0;
        red[1][wave] = r1;
        red[2][wave] = r2;
    }
    __syncthreads();
    if (threadIdx.x == 0) {
        const float s0r = red[0][0] + red[0][1] + red[0][2] + red[0][3];
        if (ch < NCCH) {
            atomicAdd(&p.ws[b], s0r);
        } else {
            atomicAdd(&p.ws[16 + b], s0r);
            atomicAdd(&p.ws[32 + b], red[1][0] + red[1][1] + red[1][2] + red[1][3]);
            atomicAdd(&p.ws[48 + b], red[2][0] + red[2][1] + red[2][2] + red[2][3]);
        }
    }

    // ---- last-block finalize ----
    __shared__ int is_last;
    if (threadIdx.x == 0) {
        __threadfence();
        const int old = __hip_atomic_fetch_add((int*)(p.ws + 64), 1,
                            __ATOMIC_ACQ_REL, __HIP_MEMORY_SCOPE_AGENT);
        is_last = (old == TOTAL_BLOCKS - 1) ? 1 : 0;
    }
    __syncthreads();
    if (is_last && threadIdx.x < 64) {
        __threadfence();
        const int t = threadIdx.x;
        float l0 = 0.f, l1 = 0.f, l2 = 0.f;
        if (t < NB) {
            const float np = fmaxf(__hip_atomic_load(&p.ws[48 + t],
                __ATOMIC_RELAXED, __HIP_MEMORY_SCOPE_AGENT), 1.0f);
            l0 = __hip_atomic_load(&p.ws[t],
                __ATOMIC_RELAXED, __HIP_MEMORY_SCOPE_AGENT) / np;
            l1 = __hip_atomic_load(&p.ws[16 + t],
                __ATOMIC_RELAXED, __HIP_MEMORY_SCOPE_AGENT) / np;
            l2 = __hip_atomic_load(&p.ws[32 + t],
                __ATOMIC_RELAXED, __HIP_MEMORY_SCOPE_AGENT) / np;
        }
        #pragma unroll
        for (int d = 32; d; d >>= 1) {
            l0 += __shfl_down(l0, d);
            l1 += __shfl_down(l1, d);
            l2 += __shfl_down(l2, d);
        }
        if (t == 0) {
            l0 *= (1.0f / NB);
            l1 *= (1.0f / NB);
            l2 *= (1.0f / NB);
            p.out[0] = l0;
            p.out[1] = l1;
            p.out[2] = l2;
            p.out[3] = l0 + l1 + l2;
        }
    }
}

extern "C" void kernel_launch(void* const* d_in, const int* in_sizes, int n_in,
                              void* d_out, int out_size, void* d_ws, size_t ws_size,
                              hipStream_t stream) {
    Ptrs p;
    for (int i = 0; i < 5; ++i) {
        p.cls[i] = (const float*)d_in[3 * i + 0];
        p.cnt[i] = (const float*)d_in[3 * i + 1];
        p.reg[i] = (const float*)d_in[3 * i + 2];
    }
    p.cnt_t = (const float*)d_in[15];
    p.reg_t = (const float*)d_in[16];
    p.cls_t = (const int*)  d_in[17];
    p.ws    = (float*)d_ws;
    p.out   = (float*)d_out;

    (void)hipMemsetAsync(d_ws, 0, 68 * sizeof(float), stream);  // sums + counter

    dim3 grid(NXQ, NCH, NB);   // 5712 workgroups
    fcos_main<<<grid, 256, 0, stream>>>(p);
}

// Round 6
// 152.695 us; speedup vs baseline: 3.3944x; 3.3944x over previous
//
#include <hip/hip_runtime.h>

#define S_TOTAL 17064
#define NB 16
#define NC 80
#define QPB 4266              // location-quads per batch image (sum hw/4)
#define NXQ 17                // quad-chunks of 256: 17*256=4352 >= 4266
#define NCCH 20               // class chunks of 4 classes each
#define NCH (NCCH + 1)        // + 1 cnt/reg chunk
#define TOTAL_BLOCKS (NXQ * NCH * NB)   // 5712
#define P1 TOTAL_BLOCKS
#define P2 (2 * TOTAL_BLOCKS)

typedef float vfloat4 __attribute__((ext_vector_type(4)));

struct Ptrs {
    const float* cls[5];
    const float* cnt[5];
    const float* reg[5];
    const float* cnt_t;   // [B,S,1]
    const float* reg_t;   // [B,S,4]
    const int*   cls_t;   // [B,S,1]
    float*       ws;      // 3 planes of TOTAL_BLOCKS floats: r0 | r1 | r2
    float*       out;
};

__device__ __forceinline__ float focal_term(float x, bool o) {
    const float xs = o ? x : -x;            // p_t = sigmoid(xs)
    const float af = o ? 0.25f : 0.75f;
    const float em = __expf(-xs);
    const float pt = 1.0f / (1.0f + em);
    const float q  = em * pt;               // 1 - p_t
    return af * q * q * __logf(1.0f + em);  // -af*(1-pt)^2*log(pt)
}

__device__ __forceinline__ float giou_term(float pl, float pt_, float pr, float pb,
                                           float tl, float tt, float tr, float tb) {
    const float overlap = fmaxf(fminf(pr, tr) + fminf(pl, tl), 0.0f) *
                          fmaxf(fminf(pb, tb) + fminf(pt_, tt), 0.0f);
    const float area1 = (pr + pl) * (pb + pt_);
    const float area2 = (tr + tl) * (tb + tt);
    const float uni = area1 + area2 - overlap;
    const float iou = overlap / uni;
    const float ga = fmaxf(fmaxf(pr, tr) + fmaxf(pl, tl), 0.0f) *
                     fmaxf(fmaxf(pb, tb) + fmaxf(pt_, tt), 0.0f);
    const float giou = iou - (ga - uni) / fmaxf(ga, 1e-10f);
    return 1.0f - giou;
}

__device__ __forceinline__ float bce_term(float x, float t) {
    return fmaxf(x, 0.0f) - x * t + __logf(1.0f + __expf(-fabsf(x)));
}

// grid: (NXQ, NCH, NB). ch<NCCH: 4-class focal chunk. ch==NCCH: cnt+GIoU chunk.
// NO atomics/fences: rounds 0-5 fit dur ~= max(work, blocks * ~65ns) -- the
// single-address device-scope ACQ_REL counter serialized every block (WRITE_SIZE
// was exactly ~64B/block of atomic writebacks, not spills). Each block now
// writes unique slots; a second kernel reduces them (stream-ordered).
__global__ __launch_bounds__(256) void fcos_main(Ptrs p) {
    const int xq = blockIdx.x;              // 0..16 quad-chunk
    const int ch = blockIdx.y;              // 0..20
    const int b  = blockIdx.z;              // 0..15
    const int fq = xq * 256 + (int)threadIdx.x;  // flat quad id within image

    // flat quad -> (level, s0)
    int lvl, qb, hw, off;
    if (fq < 3200)      { lvl = 0; qb = 0;    hw = 12800; off = 0;     }
    else if (fq < 4000) { lvl = 1; qb = 3200; hw = 3200;  off = 12800; }
    else if (fq < 4200) { lvl = 2; qb = 4000; hw = 800;   off = 16000; }
    else if (fq < 4252) { lvl = 3; qb = 4200; hw = 208;   off = 16800; }
    else                { lvl = 4; qb = 4252; hw = 56;    off = 17008; }
    const bool active = (fq < QPB);

    float r0 = 0.f, r1 = 0.f, r2 = 0.f;     // cls | (cnt, reg, pos)

    if (active) {
        const int s0  = (fq - qb) << 2;
        const int gs0 = b * S_TOTAL + off + s0;

        if (ch < NCCH) {
            // ---- 4-class focal chunk ----
            const int c0 = ch * 4;
            const int4 tq = *(const int4*)(p.cls_t + gs0);
            const float* cp = p.cls[lvl] + (size_t)((b * NC + c0) * hw + s0);

            vfloat4 buf[4];
            #pragma unroll
            for (int j = 0; j < 4; ++j)
                buf[j] = *(const vfloat4*)(cp + (size_t)(j * hw));

            float a0 = 0.f, a1 = 0.f, a2 = 0.f, a3 = 0.f;
            #pragma unroll
            for (int j = 0; j < 4; ++j) {
                const int c1 = c0 + j + 1;
                a0 += focal_term(buf[j].x, tq.x == c1);
                a1 += focal_term(buf[j].y, tq.y == c1);
                a2 += focal_term(buf[j].z, tq.z == c1);
                a3 += focal_term(buf[j].w, tq.w == c1);
            }
            r0 = (a0 + a1) + (a2 + a3);
        } else {
            // ---- cnt BCE + GIoU chunk ----
            const float4 tC  = *(const float4*)(p.cnt_t + gs0);
            const float4 xc  = *(const float4*)(p.cnt[lvl] + (size_t)(b * hw + s0));
            const float m0 = (tC.x > -1.0f) ? 1.0f : 0.0f;
            const float m1 = (tC.y > -1.0f) ? 1.0f : 0.0f;
            const float m2 = (tC.z > -1.0f) ? 1.0f : 0.0f;
            const float m3 = (tC.w > -1.0f) ? 1.0f : 0.0f;
            r2 = m0 + m1 + m2 + m3;
            r0 = bce_term(xc.x, tC.x) * m0 + bce_term(xc.y, tC.y) * m1 +
                 bce_term(xc.z, tC.z) * m2 + bce_term(xc.w, tC.w) * m3;

            const float* rp  = p.reg[lvl] + (size_t)(b * 4 * hw + s0);
            const float4 pl  = *(const float4*)(rp);
            const float4 pt_ = *(const float4*)(rp + (size_t)hw);
            const float4 pr  = *(const float4*)(rp + (size_t)(2 * hw));
            const float4 pb  = *(const float4*)(rp + (size_t)(3 * hw));
            const float4 t0  = *(const float4*)(p.reg_t + (size_t)(gs0 + 0) * 4);
            const float4 t1  = *(const float4*)(p.reg_t + (size_t)(gs0 + 1) * 4);
            const float4 t2  = *(const float4*)(p.reg_t + (size_t)(gs0 + 2) * 4);
            const float4 t3  = *(const float4*)(p.reg_t + (size_t)(gs0 + 3) * 4);

            r1 = giou_term(pl.x, pt_.x, pr.x, pb.x, t0.x, t0.y, t0.z, t0.w) * m0 +
                 giou_term(pl.y, pt_.y, pr.y, pb.y, t1.x, t1.y, t1.z, t1.w) * m1 +
                 giou_term(pl.z, pt_.z, pr.z, pb.z, t2.x, t2.y, t2.z, t2.w) * m2 +
                 giou_term(pl.w, pt_.w, pr.w, pb.w, t3.x, t3.y, t3.z, t3.w) * m3;
        }
    }

    // ---- block reduction (3 values) ----
    #pragma unroll
    for (int d = 32; d; d >>= 1) {
        r0 += __shfl_down(r0, d);
        r1 += __shfl_down(r1, d);
        r2 += __shfl_down(r2, d);
    }

    __shared__ float red[3][4];
    const int wave = threadIdx.x >> 6;
    const int lane = threadIdx.x & 63;
    if (lane == 0) {
        red[0][wave] = r0;
        red[1][wave] = r1;
        red[2][wave] = r2;
    }
    __syncthreads();
    if (threadIdx.x == 0) {
        // unique slots per block, plain cached stores -- no memset needed
        // (every block writes all 3 planes, zeros where not applicable)
        const int bid = xq + NXQ * (ch + NCH * b);
        p.ws[bid]      = red[0][0] + red[0][1] + red[0][2] + red[0][3];
        p.ws[P1 + bid] = red[1][0] + red[1][1] + red[1][2] + red[1][3];
        p.ws[P2 + bid] = red[2][0] + red[2][1] + red[2][2] + red[2][3];
    }
}

// Single-block finalize: reduces 3 planes of TOTAL_BLOCKS partials.
// Kernel boundary (same stream) guarantees visibility of fcos_main's stores.
__global__ __launch_bounds__(512) void fcos_finalize(const float* __restrict__ ws,
                                                     float* __restrict__ out) {
    __shared__ float sA[NB * NCH];   // 336 per-(b,ch) partials
    __shared__ float sB[NB * NCH];
    __shared__ float sC[NB * NCH];
    __shared__ float lb[3][NB];
    const int t = (int)threadIdx.x;

    if (t < NB * NCH) {
        const int b = t / NCH, ch = t - b * NCH;
        const int base = NXQ * (ch + NCH * b);
        float q0 = 0.f, q1 = 0.f, q2 = 0.f;
        #pragma unroll
        for (int xq = 0; xq < NXQ; ++xq) {
            q0 += ws[base + xq];
            q1 += ws[P1 + base + xq];
            q2 += ws[P2 + base + xq];
        }
        sA[t] = q0; sB[t] = q1; sC[t] = q2;
    }
    __syncthreads();

    if (t < NB) {
        const int rowbase = t * NCH;
        float cls = 0.f, reg = 0.f, pos = 0.f;
        #pragma unroll
        for (int ch = 0; ch < NCCH; ++ch) cls += sA[rowbase + ch];
        const float cnt = sA[rowbase + NCCH];
        #pragma unroll
        for (int ch = 0; ch < NCH; ++ch) { reg += sB[rowbase + ch]; pos += sC[rowbase + ch]; }
        const float np = fmaxf(pos, 1.0f);
        lb[0][t] = cls / np;
        lb[1][t] = cnt / np;
        lb[2][t] = reg / np;
    }
    __syncthreads();

    if (t == 0) {
        float l0 = 0.f, l1 = 0.f, l2 = 0.f;
        #pragma unroll
        for (int b = 0; b < NB; ++b) {
            l0 += lb[0][b]; l1 += lb[1][b]; l2 += lb[2][b];
        }
        l0 *= (1.0f / NB); l1 *= (1.0f / NB); l2 *= (1.0f / NB);
        out[0] = l0;
        out[1] = l1;
        out[2] = l2;
        out[3] = l0 + l1 + l2;
    }
}

extern "C" void kernel_launch(void* const* d_in, const int* in_sizes, int n_in,
                              void* d_out, int out_size, void* d_ws, size_t ws_size,
                              hipStream_t stream) {
    Ptrs p;
    for (int i = 0; i < 5; ++i) {
        p.cls[i] = (const float*)d_in[3 * i + 0];
        p.cnt[i] = (const float*)d_in[3 * i + 1];
        p.reg[i] = (const float*)d_in[3 * i + 2];
    }
    p.cnt_t = (const float*)d_in[15];
    p.reg_t = (const float*)d_in[16];
    p.cls_t = (const int*)  d_in[17];
    p.ws    = (float*)d_ws;
    p.out   = (float*)d_out;

    dim3 grid(NXQ, NCH, NB);   // 5712 workgroups
    fcos_main<<<grid, 256, 0, stream>>>(p);
    fcos_finalize<<<dim3(1), 512, 0, stream>>>((const float*)d_ws, (float*)d_out);
}

// Round 7
// 149.990 us; speedup vs baseline: 3.4556x; 1.0180x over previous
//
#include <hip/hip_runtime.h>

#define S_TOTAL 17064
#define NB 16
#define NC 80
#define QPB 4266              // location-quads per batch image (sum hw/4)
#define NXQ 17                // quad-chunks of 256: 17*256=4352 >= 4266
#define NCCH 10               // class chunks of 8 classes each
#define NCH (NCCH + 1)        // + 1 cnt/reg chunk
#define TOTAL_BLOCKS (NXQ * NCH * NB)   // 2992
#define P1 TOTAL_BLOCKS
#define P2 (2 * TOTAL_BLOCKS)

typedef float vfloat4 __attribute__((ext_vector_type(4)));

struct Ptrs {
    const float* cls[5];
    const float* cnt[5];
    const float* reg[5];
    const float* cnt_t;   // [B,S,1]
    const float* reg_t;   // [B,S,4]
    const int*   cls_t;   // [B,S,1]
    float*       ws;      // 3 planes of TOTAL_BLOCKS floats: r0 | r1 | r2
    float*       out;
};

__device__ __forceinline__ float focal_term(float x, bool o) {
    const float xs = o ? x : -x;            // p_t = sigmoid(xs)
    const float af = o ? 0.25f : 0.75f;
    const float em = __expf(-xs);
    const float pt = 1.0f / (1.0f + em);
    const float q  = em * pt;               // 1 - p_t
    return af * q * q * __logf(1.0f + em);  // -af*(1-pt)^2*log(pt)
}

__device__ __forceinline__ float giou_term(float pl, float pt_, float pr, float pb,
                                           float tl, float tt, float tr, float tb) {
    const float overlap = fmaxf(fminf(pr, tr) + fminf(pl, tl), 0.0f) *
                          fmaxf(fminf(pb, tb) + fminf(pt_, tt), 0.0f);
    const float area1 = (pr + pl) * (pb + pt_);
    const float area2 = (tr + tl) * (tb + tt);
    const float uni = area1 + area2 - overlap;
    const float iou = overlap / uni;
    const float ga = fmaxf(fmaxf(pr, tr) + fmaxf(pl, tl), 0.0f) *
                     fmaxf(fmaxf(pb, tb) + fmaxf(pt_, tt), 0.0f);
    const float giou = iou - (ga - uni) / fmaxf(ga, 1e-10f);
    return 1.0f - giou;
}

__device__ __forceinline__ float bce_term(float x, float t) {
    return fmaxf(x, 0.0f) - x * t + __logf(1.0f + __expf(-fabsf(x)));
}

// grid: (NXQ, NCH, NB). ch<NCCH: 8-class focal chunk. ch==NCCH: cnt+GIoU chunk.
// No atomics (r5->r6 proved the single-address ACQ_REL counter serialized all
// blocks: 371 -> <41 us). __launch_bounds__(256,4): 64-VGPR ceiling FITS the
// full working set (buf[8]=32 + tq + addr + acc ~= 50; round 1's (256,8) 32-cap
// did not) while licensing the allocator to keep all 8 loads in flight --
// every 32-VGPR build sank the loads, capping effective BW at ~3 TB/s.
__global__ __launch_bounds__(256, 4) void fcos_main(Ptrs p) {
    const int xq = blockIdx.x;              // 0..16 quad-chunk
    const int ch = blockIdx.y;              // 0..10
    const int b  = blockIdx.z;              // 0..15
    const int fq = xq * 256 + (int)threadIdx.x;  // flat quad id within image

    // flat quad -> (level, s0)
    int lvl, qb, hw, off;
    if (fq < 3200)      { lvl = 0; qb = 0;    hw = 12800; off = 0;     }
    else if (fq < 4000) { lvl = 1; qb = 3200; hw = 3200;  off = 12800; }
    else if (fq < 4200) { lvl = 2; qb = 4000; hw = 800;   off = 16000; }
    else if (fq < 4252) { lvl = 3; qb = 4200; hw = 208;   off = 16800; }
    else                { lvl = 4; qb = 4252; hw = 56;    off = 17008; }
    const bool active = (fq < QPB);

    float r0 = 0.f, r1 = 0.f, r2 = 0.f;     // cls | (cnt, reg, pos)

    if (active) {
        const int s0  = (fq - qb) << 2;
        const int gs0 = b * S_TOTAL + off + s0;

        if (ch < NCCH) {
            // ---- 8-class focal chunk: all 8 loads + tq issued up-front ----
            const int c0 = ch * 8;
            const int4 tq = *(const int4*)(p.cls_t + gs0);
            const float* cp = p.cls[lvl] + (size_t)((b * NC + c0) * hw + s0);

            vfloat4 buf[8];
            #pragma unroll
            for (int j = 0; j < 8; ++j)
                buf[j] = *(const vfloat4*)(cp + (size_t)(j * hw));

            float a0 = 0.f, a1 = 0.f, a2 = 0.f, a3 = 0.f;
            #pragma unroll
            for (int j = 0; j < 8; ++j) {
                const int c1 = c0 + j + 1;
                a0 += focal_term(buf[j].x, tq.x == c1);
                a1 += focal_term(buf[j].y, tq.y == c1);
                a2 += focal_term(buf[j].z, tq.z == c1);
                a3 += focal_term(buf[j].w, tq.w == c1);
            }
            r0 = (a0 + a1) + (a2 + a3);
        } else {
            // ---- cnt BCE + GIoU chunk ----
            const float4 tC  = *(const float4*)(p.cnt_t + gs0);
            const float4 xc  = *(const float4*)(p.cnt[lvl] + (size_t)(b * hw + s0));
            const float m0 = (tC.x > -1.0f) ? 1.0f : 0.0f;
            const float m1 = (tC.y > -1.0f) ? 1.0f : 0.0f;
            const float m2 = (tC.z > -1.0f) ? 1.0f : 0.0f;
            const float m3 = (tC.w > -1.0f) ? 1.0f : 0.0f;
            r2 = m0 + m1 + m2 + m3;
            r0 = bce_term(xc.x, tC.x) * m0 + bce_term(xc.y, tC.y) * m1 +
                 bce_term(xc.z, tC.z) * m2 + bce_term(xc.w, tC.w) * m3;

            const float* rp  = p.reg[lvl] + (size_t)(b * 4 * hw + s0);
            const float4 pl  = *(const float4*)(rp);
            const float4 pt_ = *(const float4*)(rp + (size_t)hw);
            const float4 pr  = *(const float4*)(rp + (size_t)(2 * hw));
            const float4 pb  = *(const float4*)(rp + (size_t)(3 * hw));
            const float4 t0  = *(const float4*)(p.reg_t + (size_t)(gs0 + 0) * 4);
            const float4 t1  = *(const float4*)(p.reg_t + (size_t)(gs0 + 1) * 4);
            const float4 t2  = *(const float4*)(p.reg_t + (size_t)(gs0 + 2) * 4);
            const float4 t3  = *(const float4*)(p.reg_t + (size_t)(gs0 + 3) * 4);

            r1 = giou_term(pl.x, pt_.x, pr.x, pb.x, t0.x, t0.y, t0.z, t0.w) * m0 +
                 giou_term(pl.y, pt_.y, pr.y, pb.y, t1.x, t1.y, t1.z, t1.w) * m1 +
                 giou_term(pl.z, pt_.z, pr.z, pb.z, t2.x, t2.y, t2.z, t2.w) * m2 +
                 giou_term(pl.w, pt_.w, pr.w, pb.w, t3.x, t3.y, t3.z, t3.w) * m3;
        }
    }

    // ---- block reduction (3 values) ----
    #pragma unroll
    for (int d = 32; d; d >>= 1) {
        r0 += __shfl_down(r0, d);
        r1 += __shfl_down(r1, d);
        r2 += __shfl_down(r2, d);
    }

    __shared__ float red[3][4];
    const int wave = threadIdx.x >> 6;
    const int lane = threadIdx.x & 63;
    if (lane == 0) {
        red[0][wave] = r0;
        red[1][wave] = r1;
        red[2][wave] = r2;
    }
    __syncthreads();
    if (threadIdx.x == 0) {
        // unique slots per block, plain cached stores -- no memset needed
        const int bid = xq + NXQ * (ch + NCH * b);
        p.ws[bid]      = red[0][0] + red[0][1] + red[0][2] + red[0][3];
        p.ws[P1 + bid] = red[1][0] + red[1][1] + red[1][2] + red[1][3];
        p.ws[P2 + bid] = red[2][0] + red[2][1] + red[2][2] + red[2][3];
    }
}

// Single-block finalize: reduces 3 planes of TOTAL_BLOCKS partials.
// Kernel boundary (same stream) guarantees visibility of fcos_main's stores.
__global__ __launch_bounds__(512) void fcos_finalize(const float* __restrict__ ws,
                                                     float* __restrict__ out) {
    __shared__ float sA[NB * NCH];   // 176 per-(b,ch) partials
    __shared__ float sB[NB * NCH];
    __shared__ float sC[NB * NCH];
    __shared__ float lb[3][NB];
    const int t = (int)threadIdx.x;

    if (t < NB * NCH) {
        const int b = t / NCH, ch = t - b * NCH;
        const int base = NXQ * (ch + NCH * b);
        float q0 = 0.f, q1 = 0.f, q2 = 0.f;
        #pragma unroll
        for (int xq = 0; xq < NXQ; ++xq) {
            q0 += ws[base + xq];
            q1 += ws[P1 + base + xq];
            q2 += ws[P2 + base + xq];
        }
        sA[t] = q0; sB[t] = q1; sC[t] = q2;
    }
    __syncthreads();

    if (t < NB) {
        const int rowbase = t * NCH;
        float cls = 0.f, reg = 0.f, pos = 0.f;
        #pragma unroll
        for (int ch = 0; ch < NCCH; ++ch) cls += sA[rowbase + ch];
        const float cnt = sA[rowbase + NCCH];
        #pragma unroll
        for (int ch = 0; ch < NCH; ++ch) { reg += sB[rowbase + ch]; pos += sC[rowbase + ch]; }
        const float np = fmaxf(pos, 1.0f);
        lb[0][t] = cls / np;
        lb[1][t] = cnt / np;
        lb[2][t] = reg / np;
    }
    __syncthreads();

    if (t == 0) {
        float l0 = 0.f, l1 = 0.f, l2 = 0.f;
        #pragma unroll
        for (int b = 0; b < NB; ++b) {
            l0 += lb[0][b]; l1 += lb[1][b]; l2 += lb[2][b];
        }
        l0 *= (1.0f / NB); l1 *= (1.0f / NB); l2 *= (1.0f / NB);
        out[0] = l0;
        out[1] = l1;
        out[2] = l2;
        out[3] = l0 + l1 + l2;
    }
}

extern "C" void kernel_launch(void* const* d_in, const int* in_sizes, int n_in,
                              void* d_out, int out_size, void* d_ws, size_t ws_size,
                              hipStream_t stream) {
    Ptrs p;
    for (int i = 0; i < 5; ++i) {
        p.cls[i] = (const float*)d_in[3 * i + 0];
        p.cnt[i] = (const float*)d_in[3 * i + 1];
        p.reg[i] = (const float*)d_in[3 * i + 2];
    }
    p.cnt_t = (const float*)d_in[15];
    p.reg_t = (const float*)d_in[16];
    p.cls_t = (const int*)  d_in[17];
    p.ws    = (float*)d_ws;
    p.out   = (float*)d_out;

    dim3 grid(NXQ, NCH, NB);   // 2992 workgroups
    fcos_main<<<grid, 256, 0, stream>>>(p);
    fcos_finalize<<<dim3(1), 512, 0, stream>>>((const float*)d_ws, (float*)d_out);
}